// Round 6
// baseline (17890.485 us; speedup 1.0000x reference)
//
#include <hip/hip_runtime.h>
#include <hip/hip_bf16.h>
#include <stdint.h>

// LSTM final-h. B=128, T=1024, I=256, H=512. Inputs fp32, OUTPUT FP32
// (R0-R5 forensics: d_out is float*; the "(bf16)" in the harness label is
// the threshold mode, not the out dtype).
// Persistent kernel, 128 blocks x 256 threads:
//   block = (batch-half bb) x (hidden-group hb: 8 units)
//   step: gates[64x32] = [x_t | h_{t-1}](64x768) @ W_slice^T via
//   mfma_f32_16x16x32_bf16, W_hh split hi+lo bf16, h carried hi+lo bf16.
//   c in registers; h ping-pongs in d_ws; one device barrier per step.
// R2==R3==R4 bit-identical output validated the MFMA math AND the barrier
// against an elementary fp32 pipeline.

#define Bsz 128
#define Tsz 1024
#define Isz 256
#define Hsz 512
#define NBLK 128
#define NTHREADS 256

typedef __attribute__((ext_vector_type(8))) short short8;
typedef __attribute__((ext_vector_type(4))) float float4v;

__device__ __forceinline__ float b2f(unsigned short u) {
  union { float f; unsigned int i; } v; v.i = ((unsigned int)u) << 16; return v.f;
}
__device__ __forceinline__ unsigned short f2b(float f) {
  unsigned int u = __float_as_uint(f);
  return (unsigned short)((u + 0x7fffu + ((u >> 16) & 1u)) >> 16);
}
__device__ __forceinline__ float sigmf(float x) { return 1.0f / (1.0f + __expf(-x)); }
__device__ __forceinline__ float tanhf_fast(float x) {
  float e = __expf(-2.0f * fabsf(x));
  float t = (1.0f - e) / (1.0f + e);
  return copysignf(t, x);
}
__device__ __forceinline__ short8 cvt8(const float* p) {
  float4 u = *(const float4*)(p);
  float4 v = *(const float4*)(p + 4);
  short8 r;
  r[0] = (short)f2b(u.x); r[1] = (short)f2b(u.y);
  r[2] = (short)f2b(u.z); r[3] = (short)f2b(u.w);
  r[4] = (short)f2b(v.x); r[5] = (short)f2b(v.y);
  r[6] = (short)f2b(v.z); r[7] = (short)f2b(v.w);
  return r;
}

__global__ __launch_bounds__(NTHREADS) void lstm_persistent(
    const float* __restrict__ x,
    const float* __restrict__ wih,
    const float* __restrict__ whh,
    const float* __restrict__ bih,
    const float* __restrict__ bhh,
    float* __restrict__ out,
    unsigned short* __restrict__ hhi0,
    unsigned short* __restrict__ hhi1,
    unsigned short* __restrict__ hlo0,
    unsigned short* __restrict__ hlo1,
    unsigned int* __restrict__ bar)
{
  // B-fragments, frag-ordered [nt][ks][lane] x 16B:
  __shared__ short8 whi[2 * 24 * 64];  // 48 KB: W_ih|W_hh hi
  __shared__ short8 wlo[2 * 16 * 64];  // 32 KB: W_hh lo

  const int tid  = threadIdx.x;
  const int blk  = blockIdx.x;
  const int hb   = blk & 63;   // hidden group: units j0..j0+7
  const int bb   = blk >> 6;   // batch half
  const int j0   = hb * 8;
  const int rb   = bb * 64;
  const int w    = tid >> 6;
  const int lane = tid & 63;
  const int l15  = lane & 15;
  const int kq   = lane >> 4;

  // ---- prepack W into LDS as bf16 MFMA B-fragments (hi + lo for W_hh) ----
  // local col c: 0..7=i, 8..15=f (nt0); 16..23=g, 24..31=o (nt1)
  for (int idx = tid; idx < 3072; idx += NTHREADS) {
    int nt  = (idx >= 1536) ? 1 : 0;
    int rem = idx - nt * 1536;
    int ks  = rem >> 6;        // 0..23 (0..7 x-part, 8..23 h-part)
    int ln  = rem & 63;
    int col = nt * 16 + (ln & 15);
    int k   = ks * 32 + (ln >> 4) * 8;
    int grow = (col >> 3) * Hsz + j0 + (col & 7);
    const float* src = (ks < 8) ? (wih + (size_t)grow * Isz + k)
                                : (whh + (size_t)grow * Hsz + (k - Isz));
    float wv[8];
#pragma unroll
    for (int j = 0; j < 8; ++j) wv[j] = src[j];
    short8 hi;
#pragma unroll
    for (int j = 0; j < 8; ++j) hi[j] = (short)f2b(wv[j]);
    whi[idx] = hi;
    if (ks >= 8) {
      short8 lo;
#pragma unroll
      for (int j = 0; j < 8; ++j)
        lo[j] = (short)f2b(wv[j] - b2f((unsigned short)hi[j]));
      wlo[nt * 1024 + (ks - 8) * 64 + ln] = lo;
    }
  }

  const int colA = l15;
  const int colB = 16 + l15;
  const int gA = (colA >> 3) * Hsz + j0 + (colA & 7);
  const int gB = (colB >> 3) * Hsz + j0 + (colB & 7);
  const float biasA = bih[gA] + bhh[gA];
  const float biasB = bih[gB] + bhh[gB];

  __syncthreads();

  const int arow = rb + w * 16 + l15;
  const float* xrow = x + (size_t)arow * (Tsz * Isz) + kq * 8;

  float cst[4] = {0.f, 0.f, 0.f, 0.f};
  const int rbase0 = rb + w * 16 + kq * 4;
  const int gcol   = j0 + (l15 & 7);

  for (int t = 0; t < Tsz; ++t) {
    float4v a0 = {0.f, 0.f, 0.f, 0.f};
    float4v a1 = {0.f, 0.f, 0.f, 0.f};
    const float* xp = xrow + (size_t)t * Isz;
    const unsigned short* hh = ((t & 1) ? hhi1 : hhi0) + arow * Hsz + kq * 8;
    const unsigned short* hl = ((t & 1) ? hlo1 : hlo0) + arow * Hsz + kq * 8;

#pragma unroll
    for (int ks = 0; ks < 8; ++ks) {   // x-part, K=256 (hi only)
      short8 av = cvt8(xp + ks * 32);
      short8 b0 = whi[ks * 64 + lane];
      short8 b1 = whi[1536 + ks * 64 + lane];
      a0 = __builtin_amdgcn_mfma_f32_16x16x32_bf16(av, b0, a0, 0, 0, 0);
      a1 = __builtin_amdgcn_mfma_f32_16x16x32_bf16(av, b1, a1, 0, 0, 0);
    }
#pragma unroll
    for (int ks = 0; ks < 16; ++ks) {  // h-part, K=512, hi/lo compensated
      short8 ah  = *(const short8*)(hh + ks * 32);
      short8 al  = *(const short8*)(hl + ks * 32);
      short8 bh0 = whi[(8 + ks) * 64 + lane];
      short8 bh1 = whi[1536 + (8 + ks) * 64 + lane];
      short8 bl0 = wlo[ks * 64 + lane];
      short8 bl1 = wlo[1024 + ks * 64 + lane];
      a0 = __builtin_amdgcn_mfma_f32_16x16x32_bf16(ah, bh0, a0, 0, 0, 0);
      a1 = __builtin_amdgcn_mfma_f32_16x16x32_bf16(ah, bh1, a1, 0, 0, 0);
      a0 = __builtin_amdgcn_mfma_f32_16x16x32_bf16(ah, bl0, a0, 0, 0, 0);
      a1 = __builtin_amdgcn_mfma_f32_16x16x32_bf16(ah, bl1, a1, 0, 0, 0);
      a0 = __builtin_amdgcn_mfma_f32_16x16x32_bf16(al, bh0, a0, 0, 0, 0);
      a1 = __builtin_amdgcn_mfma_f32_16x16x32_bf16(al, bh1, a1, 0, 0, 0);
    }

    // bias + gate exchange (i<->f, g<->o live in lanes l and l^8)
    float v0[4], v1[4], p0[4], p1[4];
#pragma unroll
    for (int r = 0; r < 4; ++r) {
      v0[r] = a0[r] + biasA;
      v1[r] = a1[r] + biasB;
      p0[r] = __shfl_xor(v0[r], 8, 64);
      p1[r] = __shfl_xor(v1[r], 8, 64);
    }
    if (l15 < 8) {
      unsigned short* dhh = (t & 1) ? hhi0 : hhi1;
      unsigned short* dhl = (t & 1) ? hlo0 : hlo1;
#pragma unroll
      for (int r = 0; r < 4; ++r) {
        float ig = sigmf(v0[r]);
        float fg = sigmf(p0[r]);
        float gg = tanhf_fast(v1[r]);
        float og = sigmf(p1[r]);
        float c  = fg * cst[r] + ig * gg;
        cst[r] = c;
        float hv = og * tanhf_fast(c);
        int off = (rbase0 + r) * Hsz + gcol;
        if (t == Tsz - 1) {
          out[off] = hv;                    // FP32 output
        } else {
          unsigned short hb16 = f2b(hv);
          dhh[off] = hb16;
          dhl[off] = f2b(hv - b2f(hb16));
        }
      }
    }

    if (t != Tsz - 1) {
      __syncthreads();
      if (tid == 0) {
        __threadfence();  // release: h stores visible device-wide
        unsigned int old = atomicAdd(&bar[0], 1u);
        if (old == NBLK - 1) {
          __hip_atomic_store(&bar[0], 0u, __ATOMIC_RELAXED, __HIP_MEMORY_SCOPE_AGENT);
          __hip_atomic_store(&bar[1], (unsigned)(t + 1), __ATOMIC_RELEASE, __HIP_MEMORY_SCOPE_AGENT);
        } else {
          const unsigned target = (unsigned)(t + 1);
          int guard = 0;
          while (__hip_atomic_load(&bar[1], __ATOMIC_ACQUIRE, __HIP_MEMORY_SCOPE_AGENT) < target) {
            __builtin_amdgcn_s_sleep(1);
            if (++guard > (1 << 26)) break;  // fail loud, not hang
          }
        }
        __threadfence();  // acquire: drop stale cached h lines
      }
      __syncthreads();
    }
  }
}

extern "C" void kernel_launch(void* const* d_in, const int* in_sizes, int n_in,
                              void* d_out, int out_size, void* d_ws, size_t ws_size,
                              hipStream_t stream) {
  if (n_in < 5) return;
  long long s0 = in_sizes[0], s1 = in_sizes[1], s2 = in_sizes[2],
            s3 = in_sizes[3], s4 = in_sizes[4];
  if (!(s1 > 0 && s3 > 0 && s0 == 64 * s1 && s2 == 2 * s1 &&
        s1 == 256 * s3 && s3 == s4)) return;

  const float* x   = (const float*)d_in[0];
  const float* wih = (const float*)d_in[1];
  const float* whh = (const float*)d_in[2];
  const float* bih = (const float*)d_in[3];
  const float* bhh = (const float*)d_in[4];
  float* out = (float*)d_out;

  char* ws = (char*)d_ws;
  const size_t HB = (size_t)Bsz * Hsz * 2;  // 128 KB per bf16 h buffer
  unsigned int*   bar  = (unsigned int*)ws;
  unsigned short* hhi0 = (unsigned short*)(ws + 256);
  unsigned short* hhi1 = (unsigned short*)(ws + 256 + HB);
  unsigned short* hlo0 = (unsigned short*)(ws + 256 + 2 * HB);
  unsigned short* hlo1 = (unsigned short*)(ws + 256 + 3 * HB);

  hipMemsetAsync(d_ws, 0, 256 + 4 * HB, stream);

  hipLaunchKernelGGL(lstm_persistent, dim3(NBLK), dim3(NTHREADS), 0, stream,
                     x, wih, whh, bih, bhh, out, hhi0, hhi1, hlo0, hlo1, bar);
}

// Round 7
// 13174.826 us; speedup vs baseline: 1.3579x; 1.3579x over previous
//
#include <hip/hip_runtime.h>
#include <hip/hip_bf16.h>
#include <stdint.h>

// LSTM final-h. B=128, T=1024, I=256, H=512. Inputs fp32, output fp32.
// R7: barrier rework. R6 (passing, 17.9 ms) spent ~17.5us/step in a
// 128-wide single-counter atomic barrier (serialized LLC RMWs). Now:
//  - 2 independent domains (batch halves never share h)
//  - per-block generation flags (128B-padded), wave0 polls 64 flags in
//    parallel -> one LLC round-trip per poll instead of 128 serial RMWs
//  - x-part MFMAs issued before the poll to hide arrival skew
// Numerics identical to R6 (validated: absmax 1.95e-3).

#define Bsz 128
#define Tsz 1024
#define Isz 256
#define Hsz 512
#define NBLK 128
#define NTHREADS 256

typedef __attribute__((ext_vector_type(8))) short short8;
typedef __attribute__((ext_vector_type(4))) float float4v;

__device__ __forceinline__ float b2f(unsigned short u) {
  union { float f; unsigned int i; } v; v.i = ((unsigned int)u) << 16; return v.f;
}
__device__ __forceinline__ unsigned short f2b(float f) {
  unsigned int u = __float_as_uint(f);
  return (unsigned short)((u + 0x7fffu + ((u >> 16) & 1u)) >> 16);
}
__device__ __forceinline__ float sigmf(float x) { return 1.0f / (1.0f + __expf(-x)); }
__device__ __forceinline__ float tanhf_fast(float x) {
  float e = __expf(-2.0f * fabsf(x));
  float t = (1.0f - e) / (1.0f + e);
  return copysignf(t, x);
}
__device__ __forceinline__ short8 cvt8(const float* p) {
  float4 u = *(const float4*)(p);
  float4 v = *(const float4*)(p + 4);
  short8 r;
  r[0] = (short)f2b(u.x); r[1] = (short)f2b(u.y);
  r[2] = (short)f2b(u.z); r[3] = (short)f2b(u.w);
  r[4] = (short)f2b(v.x); r[5] = (short)f2b(v.y);
  r[6] = (short)f2b(v.z); r[7] = (short)f2b(v.w);
  return r;
}

__global__ __launch_bounds__(NTHREADS) void lstm_persistent(
    const float* __restrict__ x,
    const float* __restrict__ wih,
    const float* __restrict__ whh,
    const float* __restrict__ bih,
    const float* __restrict__ bhh,
    float* __restrict__ out,
    unsigned short* __restrict__ hhi0,
    unsigned short* __restrict__ hhi1,
    unsigned short* __restrict__ hlo0,
    unsigned short* __restrict__ hlo1,
    unsigned int* __restrict__ flags)   // 2 domains x 64 flags x 32 dwords
{
  __shared__ short8 whi[2 * 24 * 64];  // 48 KB: W_ih|W_hh hi
  __shared__ short8 wlo[2 * 16 * 64];  // 32 KB: W_hh lo

  const int tid  = threadIdx.x;
  const int blk  = blockIdx.x;
  const int hb   = blk & 63;   // hidden group: units j0..j0+7; also idx in domain
  const int bb   = blk >> 6;   // batch half == sync domain
  const int j0   = hb * 8;
  const int rb   = bb * 64;
  const int w    = tid >> 6;
  const int lane = tid & 63;
  const int l15  = lane & 15;
  const int kq   = lane >> 4;

  unsigned int* dfl = flags + (size_t)bb * 64 * 32;  // this domain's flags
  unsigned int* myf = dfl + (size_t)hb * 32;         // this block's flag

  // ---- prepack W into LDS as bf16 MFMA B-fragments (hi + lo for W_hh) ----
  for (int idx = tid; idx < 3072; idx += NTHREADS) {
    int nt  = (idx >= 1536) ? 1 : 0;
    int rem = idx - nt * 1536;
    int ks  = rem >> 6;
    int ln  = rem & 63;
    int col = nt * 16 + (ln & 15);
    int k   = ks * 32 + (ln >> 4) * 8;
    int grow = (col >> 3) * Hsz + j0 + (col & 7);
    const float* src = (ks < 8) ? (wih + (size_t)grow * Isz + k)
                                : (whh + (size_t)grow * Hsz + (k - Isz));
    float wv[8];
#pragma unroll
    for (int j = 0; j < 8; ++j) wv[j] = src[j];
    short8 hi;
#pragma unroll
    for (int j = 0; j < 8; ++j) hi[j] = (short)f2b(wv[j]);
    whi[idx] = hi;
    if (ks >= 8) {
      short8 lo;
#pragma unroll
      for (int j = 0; j < 8; ++j)
        lo[j] = (short)f2b(wv[j] - b2f((unsigned short)hi[j]));
      wlo[nt * 1024 + (ks - 8) * 64 + ln] = lo;
    }
  }

  const int colA = l15;
  const int colB = 16 + l15;
  const int gA = (colA >> 3) * Hsz + j0 + (colA & 7);
  const int gB = (colB >> 3) * Hsz + j0 + (colB & 7);
  const float biasA = bih[gA] + bhh[gA];
  const float biasB = bih[gB] + bhh[gB];

  __syncthreads();

  const int arow = rb + w * 16 + l15;
  const float* xrow = x + (size_t)arow * (Tsz * Isz) + kq * 8;

  float cst[4] = {0.f, 0.f, 0.f, 0.f};
  const int rbase0 = rb + w * 16 + kq * 4;
  const int gcol   = j0 + (l15 & 7);

  for (int t = 0; t < Tsz; ++t) {
    float4v a0 = {0.f, 0.f, 0.f, 0.f};
    float4v a1 = {0.f, 0.f, 0.f, 0.f};
    const float* xp = xrow + (size_t)t * Isz;

    // ---- x-part first: independent of other blocks (hides barrier skew) ----
#pragma unroll
    for (int ks = 0; ks < 8; ++ks) {
      short8 av = cvt8(xp + ks * 32);
      short8 b0 = whi[ks * 64 + lane];
      short8 b1 = whi[1536 + ks * 64 + lane];
      a0 = __builtin_amdgcn_mfma_f32_16x16x32_bf16(av, b0, a0, 0, 0, 0);
      a1 = __builtin_amdgcn_mfma_f32_16x16x32_bf16(av, b1, a1, 0, 0, 0);
    }

    // ---- wait for step-t h from all blocks in this domain ----
    if (t > 0) {
      if (tid < 64) {
        const unsigned int* f = dfl + (size_t)tid * 32;
        int guard = 0;
        while (__hip_atomic_load(f, __ATOMIC_RELAXED, __HIP_MEMORY_SCOPE_AGENT)
               < (unsigned)t) {
          __builtin_amdgcn_s_sleep(1);
          if (++guard > (1 << 26)) break;  // fail loud, not hang
        }
      }
      __syncthreads();
      if (tid == 0) __threadfence();  // acquire: drop stale cached h lines
      __syncthreads();
    }

    const unsigned short* hh = ((t & 1) ? hhi1 : hhi0) + arow * Hsz + kq * 8;
    const unsigned short* hl = ((t & 1) ? hlo1 : hlo0) + arow * Hsz + kq * 8;

#pragma unroll
    for (int ks = 0; ks < 16; ++ks) {  // h-part, K=512, hi/lo compensated
      short8 ah  = *(const short8*)(hh + ks * 32);
      short8 al  = *(const short8*)(hl + ks * 32);
      short8 bh0 = whi[(8 + ks) * 64 + lane];
      short8 bh1 = whi[1536 + (8 + ks) * 64 + lane];
      short8 bl0 = wlo[ks * 64 + lane];
      short8 bl1 = wlo[1024 + ks * 64 + lane];
      a0 = __builtin_amdgcn_mfma_f32_16x16x32_bf16(ah, bh0, a0, 0, 0, 0);
      a1 = __builtin_amdgcn_mfma_f32_16x16x32_bf16(ah, bh1, a1, 0, 0, 0);
      a0 = __builtin_amdgcn_mfma_f32_16x16x32_bf16(ah, bl0, a0, 0, 0, 0);
      a1 = __builtin_amdgcn_mfma_f32_16x16x32_bf16(ah, bl1, a1, 0, 0, 0);
      a0 = __builtin_amdgcn_mfma_f32_16x16x32_bf16(al, bh0, a0, 0, 0, 0);
      a1 = __builtin_amdgcn_mfma_f32_16x16x32_bf16(al, bh1, a1, 0, 0, 0);
    }

    // bias + gate exchange (i<->f, g<->o live in lanes l and l^8)
    float v0[4], v1[4], p0[4], p1[4];
#pragma unroll
    for (int r = 0; r < 4; ++r) {
      v0[r] = a0[r] + biasA;
      v1[r] = a1[r] + biasB;
      p0[r] = __shfl_xor(v0[r], 8, 64);
      p1[r] = __shfl_xor(v1[r], 8, 64);
    }
    if (l15 < 8) {
      unsigned short* dhh = (t & 1) ? hhi0 : hhi1;
      unsigned short* dhl = (t & 1) ? hlo0 : hlo1;
#pragma unroll
      for (int r = 0; r < 4; ++r) {
        float ig = sigmf(v0[r]);
        float fg = sigmf(p0[r]);
        float gg = tanhf_fast(v1[r]);
        float og = sigmf(p1[r]);
        float c  = fg * cst[r] + ig * gg;
        cst[r] = c;
        float hv = og * tanhf_fast(c);
        int off = (rbase0 + r) * Hsz + gcol;
        if (t == Tsz - 1) {
          out[off] = hv;                    // fp32 output
        } else {
          unsigned short hb16 = f2b(hv);
          dhh[off] = hb16;
          dhl[off] = f2b(hv - b2f(hb16));
        }
      }
    }

    if (t != Tsz - 1) {
      __syncthreads();  // all h writes of this block done
      if (tid == 0) {
        __threadfence();  // release: flush h to coherence point (wbL2)
        __hip_atomic_store(myf, (unsigned)(t + 1),
                           __ATOMIC_RELAXED, __HIP_MEMORY_SCOPE_AGENT);
      }
      // no trailing syncthreads: next iteration's poll has its own barrier
    }
  }
}

extern "C" void kernel_launch(void* const* d_in, const int* in_sizes, int n_in,
                              void* d_out, int out_size, void* d_ws, size_t ws_size,
                              hipStream_t stream) {
  if (n_in < 5) return;
  long long s0 = in_sizes[0], s1 = in_sizes[1], s2 = in_sizes[2],
            s3 = in_sizes[3], s4 = in_sizes[4];
  if (!(s1 > 0 && s3 > 0 && s0 == 64 * s1 && s2 == 2 * s1 &&
        s1 == 256 * s3 && s3 == s4)) return;

  const float* x   = (const float*)d_in[0];
  const float* wih = (const float*)d_in[1];
  const float* whh = (const float*)d_in[2];
  const float* bih = (const float*)d_in[3];
  const float* bhh = (const float*)d_in[4];
  float* out = (float*)d_out;

  char* ws = (char*)d_ws;
  const size_t FLAGS_BYTES = 2 * 64 * 32 * 4;  // 16 KB
  const size_t HB = (size_t)Bsz * Hsz * 2;     // 128 KB per bf16 h buffer
  unsigned int*   flags = (unsigned int*)ws;
  unsigned short* hhi0 = (unsigned short*)(ws + FLAGS_BYTES);
  unsigned short* hhi1 = (unsigned short*)(ws + FLAGS_BYTES + HB);
  unsigned short* hlo0 = (unsigned short*)(ws + FLAGS_BYTES + 2 * HB);
  unsigned short* hlo1 = (unsigned short*)(ws + FLAGS_BYTES + 3 * HB);

  hipMemsetAsync(d_ws, 0, FLAGS_BYTES + 4 * HB, stream);

  hipLaunchKernelGGL(lstm_persistent, dim3(NBLK), dim3(NTHREADS), 0, stream,
                     x, wih, whh, bih, bhh, out, hhi0, hhi1, hlo0, hlo1, flags);
}